// Round 8
// baseline (243.693 us; speedup 1.0000x reference)
//
#include <hip/hip_runtime.h>

#define N_ROWS   131072
#define D_IN     256
#define D_MID    128
#define N_SUBS   64

// ws layout: rowsum[N_ROWS] floats | gbins[128] (64 group sums | 64 counts)

// K1: 4 rows per wave, straight-line (no loop-carried side effects). Four
// back-to-back float4 loads (4 KiB in flight per wave), four independent
// shfl_xor chains that interleave, then lane 0 stores all sums as one float4.
// Block 0 zeroes the group bins (consumed only by k2 -> no race).
__global__ __launch_bounds__(256) void k1_rowsum(const float* __restrict__ x,
                                                 float* __restrict__ rowsum,
                                                 float* __restrict__ bins) {
    if (blockIdx.x == 0 && threadIdx.x < 2 * N_SUBS) bins[threadIdx.x] = 0.0f;
    int wave = blockIdx.x * 4 + (threadIdx.x >> 6);
    int lane = threadIdx.x & 63;
    int row0 = wave * 4;
    const float4* p = (const float4*)(x + (size_t)row0 * D_IN);
    float4 a = p[lane];            // 4 independent 1 KiB coalesced row-loads,
    float4 b = p[64 + lane];       // all issued before any ALU dependency
    float4 c = p[128 + lane];
    float4 d = p[192 + lane];
    float s0 = (a.x + a.y) + (a.z + a.w);
    float s1 = (b.x + b.y) + (b.z + b.w);
    float s2 = (c.x + c.y) + (c.z + c.w);
    float s3 = (d.x + d.y) + (d.z + d.w);
    #pragma unroll
    for (int m = 32; m >= 1; m >>= 1) {
        s0 += __shfl_xor(s0, m, 64);   // 4 independent chains -> interleaved
        s1 += __shfl_xor(s1, m, 64);
        s2 += __shfl_xor(s2, m, 64);
        s3 += __shfl_xor(s3, m, 64);
    }
    if (lane == 0) *(float4*)(rowsum + row0) = make_float4(s0, s1, s2, s3);
}

// K2: hierarchical group binning (proven shape). 128 blocks x 256 threads;
// each thread owns 4 rows via one float4 + one int4 load, 8 LDS atomics,
// then 128 global atomics per block (16K total -> no contention wall).
__global__ __launch_bounds__(256) void k2_group(const float* __restrict__ rowsum,
                                                const int* __restrict__ sub,
                                                float* __restrict__ gbins) {
    __shared__ float ls[2 * N_SUBS];
    int tid = threadIdx.x;
    if (tid < 2 * N_SUBS) ls[tid] = 0.0f;
    __syncthreads();

    int base = (blockIdx.x * 256 + tid) * 4;
    float4 rs = *(const float4*)(rowsum + base);
    int4   sg = *(const int4*)(sub + base);
    atomicAdd(&ls[sg.x], rs.x);  atomicAdd(&ls[N_SUBS + sg.x], 1.0f);
    atomicAdd(&ls[sg.y], rs.y);  atomicAdd(&ls[N_SUBS + sg.y], 1.0f);
    atomicAdd(&ls[sg.z], rs.z);  atomicAdd(&ls[N_SUBS + sg.z], 1.0f);
    atomicAdd(&ls[sg.w], rs.w);  atomicAdd(&ls[N_SUBS + sg.w], 1.0f);

    __syncthreads();
    if (tid < 2 * N_SUBS) atomicAdd(&gbins[tid], ls[tid]);
}

// K3: 8 rows per wave, straight-line. rowsum/sub for the 8 aligned rows are
// lane-uniform float4/int4 broadcast loads (two each); per-group terms are
// L2-hot scalar loads; then 8 independent fire-and-forget 1 KiB float4
// stores (8 KiB in flight per wave). No LDS, no sync, no divergence.
__global__ __launch_bounds__(256) void k3_out(const float* __restrict__ rowsum,
                                              const int* __restrict__ sub,
                                              const float* __restrict__ gbins,
                                              const float* __restrict__ Gamma,
                                              const float* __restrict__ Lambda,
                                              float* __restrict__ out) {
    int wave = blockIdx.x * 4 + (threadIdx.x >> 6);
    int lane = threadIdx.x & 63;
    int row0 = wave * 8;
    float4 rsA = *(const float4*)(rowsum + row0);       // lane-uniform 16 B
    float4 rsB = *(const float4*)(rowsum + row0 + 4);
    int4   sgA = *(const int4*)(sub + row0);            // lane-uniform 16 B
    int4   sgB = *(const int4*)(sub + row0 + 4);
    float gam = Gamma[0], lam = Lambda[0];
    float rs0 = rowsum[0];                              // empty-group fallback

    int   g[8] = {sgA.x, sgA.y, sgA.z, sgA.w, sgB.x, sgB.y, sgB.z, sgB.w};
    float r[8] = {rsA.x, rsA.y, rsA.z, rsA.w, rsB.x, rsB.y, rsB.z, rsB.w};
    float o[8];
    #pragma unroll
    for (int j = 0; j < 8; ++j) {
        float sum = gbins[g[j]];
        float cnt = gbins[N_SUBS + g[j]];
        float meansum = (cnt > 0.0f) ? (sum / cnt) : rs0;  // mean over x[0] fallback
        float s = gam * meansum;
        s = s > 0.0f ? s : 0.0f;                           // relu
        float t = lam * (r[j] + (float)D_MID * s);
        o[j] = t > 0.0f ? t : 0.0f;                        // relu
    }
    float4* dst = (float4*)(out + (size_t)row0 * D_IN);
    #pragma unroll
    for (int j = 0; j < 8; ++j)
        dst[(size_t)j * 64 + lane] = make_float4(o[j], o[j], o[j], o[j]);
}

extern "C" void kernel_launch(void* const* d_in, const int* in_sizes, int n_in,
                              void* d_out, int out_size, void* d_ws, size_t ws_size,
                              hipStream_t stream) {
    const float* x      = (const float*)d_in[0];
    const int*   sub    = (const int*)d_in[1];
    const float* Gamma  = (const float*)d_in[2];
    const float* Lambda = (const float*)d_in[3];
    float* out = (float*)d_out;

    float* rowsum = (float*)d_ws;                 // N_ROWS floats
    float* gbins  = rowsum + N_ROWS;              // 128 floats (sums | counts)

    k1_rowsum<<<N_ROWS / 16, 256, 0, stream>>>(x, rowsum, gbins);
    k2_group<<<128, 256, 0, stream>>>(rowsum, sub, gbins);
    k3_out<<<N_ROWS / 32, 256, 0, stream>>>(rowsum, sub, gbins, Gamma, Lambda, out);
}